// Round 2
// baseline (5013.349 us; speedup 1.0000x reference)
//
#include <hip/hip_runtime.h>
#include <hip/hip_fp16.h>

#define H 161
#define G4 644            // 4*H gates
#define BB 32             // batch
#define TT 1000           // time
#define M_TOT (BB*TT)     // 32000 rows
#define NPAIR 84          // half2 pairs covering K padded to 168
#define NVEC (NPAIR/4)    // 21 uint4 reads of the h vector
#define NROWL 322         // active lanes in scan (2 rows each)

typedef _Float16 h2_t __attribute__((ext_vector_type(2)));

__device__ __forceinline__ h2_t bc_h2(unsigned int u) {
    return __builtin_bit_cast(h2_t, u);
}

__device__ __forceinline__ float dot2f(h2_t a, h2_t b, float c) {
#if __has_builtin(__builtin_amdgcn_fdot2)
    return __builtin_amdgcn_fdot2(a, b, c, false);
#else
    return c + (float)a[0] * (float)b[0] + (float)a[1] * (float)b[1];
#endif
}

__device__ __forceinline__ float sigm_f(float x) {
    return 1.0f / (1.0f + __expf(-x));
}
__device__ __forceinline__ float tanh_f(float x) {
    return 1.0f - 2.0f / (__expf(2.0f * x) + 1.0f);
}

// ---------------------------------------------------------------------------
// pre_gemm: pre[d][m][g] = sum_k A[m][k] * wih_d[g][k] + bih_d[g] + bhh_d[g]
// ---------------------------------------------------------------------------
__global__ __launch_bounds__(256) void pre_gemm(
    const float* __restrict__ A,
    const float* __restrict__ wf, const float* __restrict__ wb,
    const float* __restrict__ bif, const float* __restrict__ bhf,
    const float* __restrict__ bib, const float* __restrict__ bhb,
    __half* __restrict__ pre)
{
    const int BM = 64, BN = 64, BK = 16;
    int m0 = blockIdx.x * BM;
    int n0 = blockIdx.y * BN;
    __shared__ float As[BK][BM + 1];
    __shared__ float Bs[BK][BN + 1];
    int tid = threadIdx.x;
    int tx = tid & 15, ty = tid >> 4;
    float acc[4][4] = {};

    for (int k0 = 0; k0 < H; k0 += BK) {
        #pragma unroll
        for (int l = 0; l < (BM * BK) / 256; ++l) {
            int e = tid + l * 256;
            int mm = e / BK, kk = e % BK;
            int k = k0 + kk;
            As[kk][mm] = (k < H) ? A[(size_t)(m0 + mm) * H + k] : 0.f;
        }
        #pragma unroll
        for (int l = 0; l < (BN * BK) / 256; ++l) {
            int e = tid + l * 256;
            int nn = e / BK, kk = e % BK;
            int n = n0 + nn, k = k0 + kk;
            float v = 0.f;
            if (k < H && n < 2 * G4)
                v = (n < G4) ? wf[(size_t)n * H + k] : wb[(size_t)(n - G4) * H + k];
            Bs[kk][nn] = v;
        }
        __syncthreads();
        #pragma unroll
        for (int kk = 0; kk < BK; ++kk) {
            float a4[4], b4[4];
            #pragma unroll
            for (int i = 0; i < 4; ++i) a4[i] = As[kk][ty + 16 * i];
            #pragma unroll
            for (int j = 0; j < 4; ++j) b4[j] = Bs[kk][tx + 16 * j];
            #pragma unroll
            for (int i = 0; i < 4; ++i)
                #pragma unroll
                for (int j = 0; j < 4; ++j) acc[i][j] += a4[i] * b4[j];
        }
        __syncthreads();
    }

    #pragma unroll
    for (int i = 0; i < 4; ++i) {
        int m = m0 + ty + 16 * i;
        #pragma unroll
        for (int j = 0; j < 4; ++j) {
            int n = n0 + tx + 16 * j;
            if (n < 2 * G4) {
                int d = (n >= G4) ? 1 : 0;
                int g = n - d * G4;
                float bias = d ? (bib[g] + bhb[g]) : (bif[g] + bhf[g]);
                pre[((size_t)d * M_TOT + m) * G4 + g] = __float2half(acc[i][j] + bias);
            }
        }
    }
}

// ---------------------------------------------------------------------------
// lstm_scan: one block per (batch, direction). 384 threads (6 waves);
// lanes 0..321 each own TWO gate rows (g=tid and g=tid+322) held in VGPRs
// as packed half2. h kept in LDS as f16; per-step LDS broadcast traffic is
// halved vs 1-row/lane (126 ds_read_b128 instead of 231). pre[t+1] is
// register-prefetched at loop top to pull global latency off the chain.
// Row g=tid   in [0,322)   -> i or f gate -> always sigmoid.
// Row g=tid+322 in [322,644) -> g gate (tanh) iff tid<161, else o (sigmoid).
// ---------------------------------------------------------------------------
__global__ __launch_bounds__(384, 2) void lstm_scan(
    const __half* __restrict__ pre,      // [2][M_TOT][G4]
    const float* __restrict__ whh_f,
    const float* __restrict__ whh_b,
    float* __restrict__ hcat)            // [M_TOT][2*H]
{
    const int b = blockIdx.x;            // 0..31
    const int d = blockIdx.y;            // 0,1
    const int tid = threadIdx.x;
    const float* whh = d ? whh_b : whh_f;

    __shared__ __align__(16) unsigned int h_sh[NPAIR];  // 168 halves
    __shared__ float gate_sh[G4];

    const bool active = tid < NROWL;
    h2_t w0[NPAIR], w1[NPAIR];
    if (active) {
        const float* r0 = whh + (size_t)tid * H;
        const float* r1 = whh + (size_t)(tid + NROWL) * H;
        #pragma unroll
        for (int i = 0; i < NPAIR; ++i) {
            float a0 = (2 * i < H) ? r0[2 * i] : 0.f;
            float a1 = (2 * i + 1 < H) ? r0[2 * i + 1] : 0.f;
            float b0 = (2 * i < H) ? r1[2 * i] : 0.f;
            float b1 = (2 * i + 1 < H) ? r1[2 * i + 1] : 0.f;
            h2_t v0; v0[0] = (_Float16)a0; v0[1] = (_Float16)a1;
            h2_t v1; v1[0] = (_Float16)b0; v1[1] = (_Float16)b1;
            w0[i] = v0; w1[i] = v1;
        }
    }
    if (tid < NPAIR) h_sh[tid] = 0u;
    float c = 0.f;
    const size_t base = ((size_t)d * M_TOT + (size_t)b * TT) * G4;
    const bool g1_tanh = tid < H;        // row tid+322 lies in the g-gate range
    __syncthreads();

    // prefetch step 0
    __half p0 = __float2half(0.f), p1 = p0;
    {
        int t0 = d ? (TT - 1) : 0;
        if (active) {
            p0 = pre[base + (size_t)t0 * G4 + tid];
            p1 = pre[base + (size_t)t0 * G4 + tid + NROWL];
        }
    }

    for (int ttt = 0; ttt < TT; ++ttt) {
        int t = d ? (TT - 1 - ttt) : ttt;
        // issue next-step prefetch first so it overlaps everything below
        __half p0n = __float2half(0.f), p1n = p0n;
        if (active && (ttt + 1 < TT)) {
            int tn = d ? (TT - 2 - ttt) : (ttt + 1);
            p0n = pre[base + (size_t)tn * G4 + tid];
            p1n = pre[base + (size_t)tn * G4 + tid + NROWL];
        }
        if (active) {
            float a00 = 0.f, a01 = 0.f, a02 = 0.f, a03 = 0.f;
            float a10 = 0.f, a11 = 0.f, a12 = 0.f, a13 = 0.f;
            const uint4* hv = (const uint4*)h_sh;
            #pragma unroll
            for (int i = 0; i < NVEC; ++i) {
                uint4 hh = hv[i];
                a00 = dot2f(w0[4 * i + 0], bc_h2(hh.x), a00);
                a01 = dot2f(w0[4 * i + 1], bc_h2(hh.y), a01);
                a02 = dot2f(w0[4 * i + 2], bc_h2(hh.z), a02);
                a03 = dot2f(w0[4 * i + 3], bc_h2(hh.w), a03);
                a10 = dot2f(w1[4 * i + 0], bc_h2(hh.x), a10);
                a11 = dot2f(w1[4 * i + 1], bc_h2(hh.y), a11);
                a12 = dot2f(w1[4 * i + 2], bc_h2(hh.z), a12);
                a13 = dot2f(w1[4 * i + 3], bc_h2(hh.w), a13);
            }
            float acc0 = __half2float(p0) + (a00 + a01) + (a02 + a03);
            float acc1 = __half2float(p1) + (a10 + a11) + (a12 + a13);
            gate_sh[tid] = sigm_f(acc0);
            gate_sh[tid + NROWL] = g1_tanh ? tanh_f(acc1) : sigm_f(acc1);
        }
        __syncthreads();
        if (tid < H) {
            float ig = gate_sh[tid];
            float fg = gate_sh[tid + H];
            float gg = gate_sh[tid + 2 * H];
            float og = gate_sh[tid + 3 * H];
            c = fg * c + ig * gg;
            float h = og * tanh_f(c);
            hcat[((size_t)b * TT + t) * (2 * H) + (size_t)d * H + tid] = h;
            ((__half*)h_sh)[tid] = __float2half(h);
        }
        __syncthreads();
        p0 = p0n; p1 = p1n;
    }
}

// ---------------------------------------------------------------------------
// lin_gemm: out[m][n] = relu?(sum_k hcat[m][k]*W[n][k] + bl[n]) + res[m][n]
// ---------------------------------------------------------------------------
__global__ __launch_bounds__(256) void lin_gemm(
    const float* __restrict__ A,     // [M_TOT][2H]
    const float* __restrict__ W,     // [H][2H]
    const float* __restrict__ bl,    // [H]
    const float* __restrict__ res,   // [M_TOT][H]
    float* __restrict__ out,         // [M_TOT][H]
    int relu)
{
    const int BM = 64, BN = 64, BK = 16;
    const int K = 2 * H;
    int m0 = blockIdx.x * BM;
    int n0 = blockIdx.y * BN;
    __shared__ float As[BK][BM + 1];
    __shared__ float Bs[BK][BN + 1];
    int tid = threadIdx.x;
    int tx = tid & 15, ty = tid >> 4;
    float acc[4][4] = {};

    for (int k0 = 0; k0 < K; k0 += BK) {
        #pragma unroll
        for (int l = 0; l < (BM * BK) / 256; ++l) {
            int e = tid + l * 256;
            int mm = e / BK, kk = e % BK;
            int k = k0 + kk;
            As[kk][mm] = (k < K) ? A[(size_t)(m0 + mm) * K + k] : 0.f;
        }
        #pragma unroll
        for (int l = 0; l < (BN * BK) / 256; ++l) {
            int e = tid + l * 256;
            int nn = e / BK, kk = e % BK;
            int n = n0 + nn, k = k0 + kk;
            Bs[kk][nn] = (k < K && n < H) ? W[(size_t)n * K + k] : 0.f;
        }
        __syncthreads();
        #pragma unroll
        for (int kk = 0; kk < BK; ++kk) {
            float a4[4], b4[4];
            #pragma unroll
            for (int i = 0; i < 4; ++i) a4[i] = As[kk][ty + 16 * i];
            #pragma unroll
            for (int j = 0; j < 4; ++j) b4[j] = Bs[kk][tx + 16 * j];
            #pragma unroll
            for (int i = 0; i < 4; ++i)
                #pragma unroll
                for (int j = 0; j < 4; ++j) acc[i][j] += a4[i] * b4[j];
        }
        __syncthreads();
    }

    #pragma unroll
    for (int i = 0; i < 4; ++i) {
        int m = m0 + ty + 16 * i;
        #pragma unroll
        for (int j = 0; j < 4; ++j) {
            int n = n0 + tx + 16 * j;
            if (n < H) {
                float v = acc[i][j] + bl[n];
                if (relu) v = fmaxf(v, 0.f);
                v += res[(size_t)m * H + n];
                out[(size_t)m * H + n] = v;
            }
        }
    }
}

extern "C" void kernel_launch(void* const* d_in, const int* in_sizes, int n_in,
                              void* d_out, int out_size, void* d_ws, size_t ws_size,
                              hipStream_t stream) {
    const float* x = (const float*)d_in[0];

    char* ws = (char*)d_ws;
    __half* pre = (__half*)ws;                                   // 2*32000*644 halves
    float* hcat = (float*)(ws + (size_t)2 * M_TOT * G4 * sizeof(__half));
    float* bufA = hcat + (size_t)M_TOT * 2 * H;
    float* bufB = bufA + (size_t)M_TOT * H;

    const float* cur = x;
    float* outs[3] = {bufA, bufB, (float*)d_out};

    for (int l = 0; l < 3; ++l) {
        const float* const* p = (const float* const*)(d_in + 1 + 10 * l);
        // p: wih_f whh_f bih_f bhh_f wih_b whh_b bih_b bhh_b W bl
        dim3 g1(M_TOT / 64, 21);
        pre_gemm<<<g1, 256, 0, stream>>>(cur, p[0], p[4], p[2], p[3], p[6], p[7], pre);
        lstm_scan<<<dim3(32, 2), 384, 0, stream>>>(pre, p[1], p[5], hcat);
        dim3 g2(M_TOT / 64, 3);
        lin_gemm<<<g2, 256, 0, stream>>>(hcat, p[8], p[9], cur, outs[l], (l < 2) ? 1 : 0);
        cur = outs[l];
    }
}